// Round 4
// baseline (975.684 us; speedup 1.0000x reference)
//
#include <hip/hip_runtime.h>

#define NN 100000   // nodes
#define NE 640000   // edges
#define RR 8        // relations
#define NBIN 800000 // NN*8 csr bins (permuted key space)
// D = HID = OUT = 128 hard-coded below.

typedef unsigned short u16;
typedef u16 u16x4 __attribute__((ext_vector_type(4)));
typedef u16 u16x8 __attribute__((ext_vector_type(8)));
typedef __bf16 bf16x8 __attribute__((ext_vector_type(8)));
typedef float f32x4 __attribute__((ext_vector_type(4)));

// ---- workspace layout (bytes) ----
#define OFF_MSG     0u          // fp32 N*128            = 51,200,000
#define OFF_MIDB    51200000u   // bf16 N*256            = 51,200,000
#define OFF_XB      102400000u  // bf16 N*128            = 25,600,000
#define OFF_WT      128000000u  // bf16 [9][128o][128d]  = 294,912 (8 rels + loop_w)
#define OFF_W1T     128296960u  // bf16 [256o][256i]     = 131,072
#define OFF_W2T     128428032u  // bf16 [128o][384i]     = 98,304
#define OFF_BUCKET  128527360u  // uint E (packed)       = 2,560,000
#define OFF_CSROFF  131088384u  // int  NBIN+1           = 3,200,004
#define OFF_CUR     134289408u  // int  NBIN             = 3,200,000
#define OFF_PSUM    137490432u  // int  1024

__device__ inline u16 f2bf(float f) {
  unsigned u = __float_as_uint(f);
  u += 0x7FFF + ((u >> 16) & 1);   // round-to-nearest-even
  return (u16)(u >> 16);
}
__device__ inline float bf2f(u16 h) { return __uint_as_float(((unsigned)h) << 16); }

// sort key: bin = (tile*2 + phase)*128 + (dst&31)*4 + (et&3)
// -> each block's (tile, phase) edge set is CONTIGUOUS in bucket[]
__device__ inline int edge_bin(int d, int r) {
  return (((d >> 5) * 2 + (r >> 2)) << 7) + ((d & 31) << 2) + (r & 3);
}

// ---------------- dtype prep ----------------
__global__ void k_cvt_x(const float* __restrict__ x, u16* __restrict__ xb) {
  const int i = (blockIdx.x * 256 + threadIdx.x) * 4;
  const float4 v = *(const float4*)(x + i);
  u16x4 o;
  o.x = f2bf(v.x); o.y = f2bf(v.y); o.z = f2bf(v.z); o.w = f2bf(v.w);
  *(u16x4*)(xb + i) = o;
}

// Wt[r][o][d]: r<8 from W_rel, r==8 from loop_w
__global__ void k_cvt_wrel(const float* __restrict__ W, const float* __restrict__ Lw,
                           u16* __restrict__ Wt) {
  const int idx = blockIdx.x * 256 + threadIdx.x;      // 9*16384 total
  const int r = idx >> 14, o = (idx >> 7) & 127, d = idx & 127;
  Wt[idx] = f2bf(r < 8 ? W[(r << 14) + (d << 7) + o] : Lw[(d << 7) + o]);
}

__global__ void k_cvt_w1(const float* __restrict__ W1, u16* __restrict__ W1t) {
  const int idx = blockIdx.x * 256 + threadIdx.x;      // 65536
  const int o = idx >> 8, i = idx & 255;
  W1t[idx] = f2bf(W1[i * 256 + o]);
}

__global__ void k_cvt_w2(const float* __restrict__ W2, u16* __restrict__ W2t) {
  const int idx = blockIdx.x * 256 + threadIdx.x;      // 49152
  const int o = idx / 384, i = idx % 384;
  W2t[idx] = f2bf(W2[i * 128 + o]);
}

// ---------------- CSR build ----------------
__global__ void k_hist(const int* __restrict__ dst, const int* __restrict__ et,
                       int* __restrict__ cnt) {
  const int e = blockIdx.x * 256 + threadIdx.x;
  if (e < NE) atomicAdd(&cnt[edge_bin(dst[e], et[e])], 1);
}

__global__ void k_scanA(const int* __restrict__ cnt, int* __restrict__ psum) {
  __shared__ int sc[256];
  const int tid = threadIdx.x, base = blockIdx.x * 1024 + tid * 4;
  int s = 0;
#pragma unroll
  for (int t = 0; t < 4; ++t) { const int i = base + t; if (i < NBIN) s += cnt[i]; }
  sc[tid] = s; __syncthreads();
  for (int d = 128; d > 0; d >>= 1) {
    if (tid < d) sc[tid] += sc[tid + d];
    __syncthreads();
  }
  if (tid == 0) psum[blockIdx.x] = sc[0];
}

__global__ void k_scanB(int* __restrict__ psum) {
  __shared__ int sc[1024];
  const int tid = threadIdx.x;
  const int v = (tid < 782) ? psum[tid] : 0;
  sc[tid] = v; __syncthreads();
  for (int d = 1; d < 1024; d <<= 1) {
    const int t = (tid >= d) ? sc[tid - d] : 0;
    __syncthreads();
    sc[tid] += t;
    __syncthreads();
  }
  if (tid < 782) psum[tid] = sc[tid] - v;   // exclusive
}

__global__ void k_scanC(int* __restrict__ cnt /*=cur*/, const int* __restrict__ psum,
                        int* __restrict__ off) {
  __shared__ int sc[256];
  const int tid = threadIdx.x, base = blockIdx.x * 1024 + tid * 4;
  int c[4], s = 0;
#pragma unroll
  for (int t = 0; t < 4; ++t) {
    const int i = base + t;
    c[t] = (i < NBIN) ? cnt[i] : 0;
    s += c[t];
  }
  sc[tid] = s; __syncthreads();
  for (int d = 1; d < 256; d <<= 1) {
    const int t = (tid >= d) ? sc[tid - d] : 0;
    __syncthreads();
    sc[tid] += t;
    __syncthreads();
  }
  int run = psum[blockIdx.x] + sc[tid] - s;   // exclusive thread base
#pragma unroll
  for (int t = 0; t < 4; ++t) {
    const int i = base + t;
    if (i < NBIN) { off[i] = run; cnt[i] = run; run += c[t]; }
  }
  if (blockIdx.x == 0 && tid == 0) off[NBIN] = NE;
}

__global__ void k_scatter(const int* __restrict__ src, const int* __restrict__ dst,
                          const int* __restrict__ et, int* __restrict__ cur,
                          unsigned* __restrict__ bucket) {
  const int e = blockIdx.x * 256 + threadIdx.x;
  if (e < NE) {
    const int d = dst[e], r = et[e];
    const int pos = atomicAdd(&cur[edge_bin(d, r)], 1);
    // pack: src (17b) | dst&31 (5b) | et&3 (2b)
    bucket[pos] = (unsigned)src[e] | ((unsigned)(d & 31) << 17) | ((unsigned)(r & 3) << 22);
  }
}

// ---------------- fused edge-aggregate + transform + self-loop + bias ----
// One block per 32 dst nodes. 2 gather phases (4 rels each, edge-parallel,
// LDS fp32 atomic accumulate) + self-loop from global. Zero global atomics.
#define ACCS 132   // fp32 row stride: 132%32=4 -> 2-way bank pattern (free)
__global__ __launch_bounds__(256) void k_edge_msg(
    const u16* __restrict__ xb, const u16* __restrict__ Wt,
    const int* __restrict__ csroff, const unsigned* __restrict__ bucket,
    const float* __restrict__ rel_bias, float* __restrict__ msg) {
  __shared__ float accF[4 * 32 * ACCS];   // 67,584 B -> 2 blocks/CU
  const int tid = threadIdx.x;
  const int v0 = blockIdx.x * 32;
  const int wave = tid >> 6, lane = tid & 63;
  const int l16 = lane & 15, quad = lane >> 4;
  const int rt = wave & 1, cb = (wave >> 1) << 6;

  const int base0 = csroff[blockIdx.x * 256];
  const int base1 = csroff[blockIdx.x * 256 + 128];
  const int base2 = csroff[blockIdx.x * 256 + 256];

  f32x4 acc[4] = {};

  // ---- self-loop: A-frags straight from global xb (already bf16) ----
  {
    const u16* xp = xb + ((size_t)(v0 + rt * 16 + l16) << 7) + quad * 8;
    bf16x8 afr[4];
#pragma unroll
    for (int t = 0; t < 4; ++t) afr[t] = *(const bf16x8*)(xp + t * 32);
    const u16* wb = Wt + (8 << 14);
#pragma unroll
    for (int c = 0; c < 4; ++c) {
      const u16* wp = wb + (size_t)(cb + c * 16 + l16) * 128 + quad * 8;
#pragma unroll
      for (int t = 0; t < 4; ++t)
        acc[c] = __builtin_amdgcn_mfma_f32_16x16x32_bf16(afr[t], *(const bf16x8*)(wp + t * 32), acc[c], 0, 0, 0);
    }
  }

#pragma unroll
  for (int ph = 0; ph < 2; ++ph) {
    // zero accumulator
    for (int i = tid; i < 4 * 32 * ACCS / 4; i += 256)
      *(f32x4*)&accF[i * 4] = (f32x4){0.f, 0.f, 0.f, 0.f};
    __syncthreads();

    // edge-parallel gather: task = (edge, 16-col group)
    const int pstart = ph ? base1 : base0;
    const int nt = ((ph ? base2 : base1) - pstart) * 8;
    for (int t = tid; t < nt; t += 256) {
      const unsigned w = bucket[pstart + (t >> 3)];
      const int sj = t & 7;
      const u16* xp = xb + ((size_t)(w & 131071u) << 7) + sj * 16;
      const u16x8 h0 = *(const u16x8*)(xp);
      const u16x8 h1 = *(const u16x8*)(xp + 8);
      float* ac = accF + ((w >> 22) & 3u) * (32 * ACCS) + ((w >> 17) & 31u) * ACCS + sj * 16;
#pragma unroll
      for (int i = 0; i < 8; ++i) {
        atomicAdd(ac + i,     bf2f(h0[i]));
        atomicAdd(ac + 8 + i, bf2f(h1[i]));
      }
    }
    __syncthreads();

    // MFMA: 4 relations, A read from fp32 accum with in-reg bf16 convert
#pragma unroll
    for (int q = 0; q < 4; ++q) {
      const int r = ph * 4 + q;
      bf16x8 afr[4];
#pragma unroll
      for (int t = 0; t < 4; ++t) {
        const int off = q * (32 * ACCS) + (rt * 16 + l16) * ACCS + quad * 8 + t * 32;
        const f32x4 a0 = *(const f32x4*)&accF[off];
        const f32x4 a1 = *(const f32x4*)&accF[off + 4];
        union { u16x8 u; bf16x8 b; } cv;
        cv.u[0] = f2bf(a0[0]); cv.u[1] = f2bf(a0[1]); cv.u[2] = f2bf(a0[2]); cv.u[3] = f2bf(a0[3]);
        cv.u[4] = f2bf(a1[0]); cv.u[5] = f2bf(a1[1]); cv.u[6] = f2bf(a1[2]); cv.u[7] = f2bf(a1[3]);
        afr[t] = cv.b;
      }
      const u16* wb = Wt + (r << 14);
#pragma unroll
      for (int c = 0; c < 4; ++c) {
        const u16* wp = wb + (size_t)(cb + c * 16 + l16) * 128 + quad * 8;
#pragma unroll
        for (int t = 0; t < 4; ++t)
          acc[c] = __builtin_amdgcn_mfma_f32_16x16x32_bf16(afr[t], *(const bf16x8*)(wp + t * 32), acc[c], 0, 0, 0);
      }
    }
    __syncthreads();
  }

  // ---- epilogue: + rel_bias, single fp32 write ----
#pragma unroll
  for (int c = 0; c < 4; ++c) {
    const int col = cb + c * 16 + l16;
    const float bias = rel_bias[col];
#pragma unroll
    for (int reg = 0; reg < 4; ++reg) {
      const int row = v0 + rt * 16 + quad * 4 + reg;
      msg[(size_t)row * 128 + col] = acc[c][reg] + bias;
    }
  }
}

// ---------------- mid = tanh([x | msg] @ W1 + b1), bf16 MFMA -------------
#define A1S 264   // 256+8 u16: 132 words, %32=4
__global__ __launch_bounds__(256) void k_mlp1(
    const u16* __restrict__ xb, const float* __restrict__ msg,
    const u16* __restrict__ W1t, const float* __restrict__ b1,
    u16* __restrict__ midb) {
  __shared__ u16 At[32 * A1S];
  const int tid = threadIdx.x;
  const int v0 = blockIdx.x * 32;
  const int si = tid >> 3, sj = tid & 7;

  { // stage x -> cols 0..127
    const u16* xp = xb + ((size_t)(v0 + si) << 7) + sj * 16;
    *(u16x8*)&At[si * A1S + sj * 16]     = *(const u16x8*)(xp);
    *(u16x8*)&At[si * A1S + sj * 16 + 8] = *(const u16x8*)(xp + 8);
  }
  { // stage msg (fp32) -> cols 128..255
    const float* mp = msg + (size_t)(v0 + si) * 128 + sj * 16;
    u16x8 o0, o1;
#pragma unroll
    for (int t = 0; t < 8; ++t) { o0[t] = f2bf(mp[t]); o1[t] = f2bf(mp[8 + t]); }
    *(u16x8*)&At[si * A1S + 128 + sj * 16]     = o0;
    *(u16x8*)&At[si * A1S + 128 + sj * 16 + 8] = o1;
  }
  __syncthreads();

  const int wave = tid >> 6, lane = tid & 63;
  const int l16 = lane & 15, quad = lane >> 4;
  const int rt = wave & 1, ch = (wave >> 1) << 7;

  f32x4 acc[8] = {};
  for (int kt = 0; kt < 8; ++kt) {
    const bf16x8 af = *(const bf16x8*)&At[(rt * 16 + l16) * A1S + kt * 32 + quad * 8];
#pragma unroll
    for (int ct = 0; ct < 8; ++ct) {
      const u16* wp = W1t + (size_t)(ch + ct * 16 + l16) * 256 + kt * 32 + quad * 8;
      acc[ct] = __builtin_amdgcn_mfma_f32_16x16x32_bf16(af, *(const bf16x8*)(wp), acc[ct], 0, 0, 0);
    }
  }

#pragma unroll
  for (int ct = 0; ct < 8; ++ct) {
    const int col = ch + ct * 16 + l16;
    const float bias = b1[col];
#pragma unroll
    for (int reg = 0; reg < 4; ++reg) {
      const int row = v0 + rt * 16 + quad * 4 + reg;
      midb[(size_t)row * 256 + col] = f2bf(tanhf(acc[ct][reg] + bias));
    }
  }
}

// ---------------- out = [x | mid] @ W2 + b2, bf16 MFMA -------------------
#define A2S 392   // 384+8 u16: 196 words, %32=4
__global__ __launch_bounds__(256) void k_mlp2(
    const u16* __restrict__ xb, const u16* __restrict__ midb,
    const u16* __restrict__ W2t, const float* __restrict__ b2,
    float* __restrict__ out) {
  __shared__ u16 At[32 * A2S];
  const int tid = threadIdx.x;
  const int v0 = blockIdx.x * 32;
  const int si = tid >> 3, sj = tid & 7;

  { // stage x -> cols 0..127
    const u16* xp = xb + ((size_t)(v0 + si) << 7) + sj * 16;
    *(u16x8*)&At[si * A2S + sj * 16]     = *(const u16x8*)(xp);
    *(u16x8*)&At[si * A2S + sj * 16 + 8] = *(const u16x8*)(xp + 8);
  }
  { // stage mid -> cols 128..383 (32 u16 per thread)
    const u16* mp = midb + ((size_t)(v0 + si) << 8) + sj * 32;
#pragma unroll
    for (int t = 0; t < 4; ++t)
      *(u16x8*)&At[si * A2S + 128 + sj * 32 + t * 8] = *(const u16x8*)(mp + t * 8);
  }
  __syncthreads();

  const int wave = tid >> 6, lane = tid & 63;
  const int l16 = lane & 15, quad = lane >> 4;
  const int rt = wave & 1, cb = (wave >> 1) << 6;

  f32x4 acc[4] = {};
  for (int kt = 0; kt < 12; ++kt) {
    const bf16x8 af = *(const bf16x8*)&At[(rt * 16 + l16) * A2S + kt * 32 + quad * 8];
#pragma unroll
    for (int ct = 0; ct < 4; ++ct) {
      const u16* wp = W2t + (size_t)(cb + ct * 16 + l16) * 384 + kt * 32 + quad * 8;
      acc[ct] = __builtin_amdgcn_mfma_f32_16x16x32_bf16(af, *(const bf16x8*)(wp), acc[ct], 0, 0, 0);
    }
  }

#pragma unroll
  for (int ct = 0; ct < 4; ++ct) {
    const int col = cb + ct * 16 + l16;
    const float bias = b2[col];
#pragma unroll
    for (int reg = 0; reg < 4; ++reg) {
      const int row = v0 + rt * 16 + quad * 4 + reg;
      out[(size_t)row * 128 + col] = acc[ct][reg] + bias;
    }
  }
}

extern "C" void kernel_launch(void* const* d_in, const int* in_sizes, int n_in,
                              void* d_out, int out_size, void* d_ws, size_t ws_size,
                              hipStream_t stream) {
  (void)in_sizes; (void)n_in; (void)out_size; (void)ws_size;
  const float* x        = (const float*)d_in[0];
  const int*   src      = (const int*)d_in[1];
  const int*   dst      = (const int*)d_in[2];
  const int*   et       = (const int*)d_in[3];
  const float* W_rel    = (const float*)d_in[4];
  const float* loop_w   = (const float*)d_in[5];
  const float* rel_bias = (const float*)d_in[6];
  const float* W1       = (const float*)d_in[7];
  const float* b1       = (const float*)d_in[8];
  const float* W2       = (const float*)d_in[9];
  const float* b2       = (const float*)d_in[10];
  float* out = (float*)d_out;

  char* ws = (char*)d_ws;
  float*    msg    = (float*)(ws + OFF_MSG);
  u16*      midb   = (u16*)(ws + OFF_MIDB);
  u16*      xb     = (u16*)(ws + OFF_XB);
  u16*      Wt     = (u16*)(ws + OFF_WT);
  u16*      W1t    = (u16*)(ws + OFF_W1T);
  u16*      W2t    = (u16*)(ws + OFF_W2T);
  unsigned* bucket = (unsigned*)(ws + OFF_BUCKET);
  int*      csroff = (int*)(ws + OFF_CSROFF);
  int*      cur    = (int*)(ws + OFF_CUR);
  int*      psum   = (int*)(ws + OFF_PSUM);

  hipMemsetAsync(cur, 0, (size_t)NBIN * 4, stream);

  k_cvt_x   <<<(NN * 128) / 1024, 256, 0, stream>>>(x, xb);
  k_cvt_wrel<<<(9 * 16384) / 256, 256, 0, stream>>>(W_rel, loop_w, Wt);
  k_cvt_w1  <<<(256 * 256) / 256, 256, 0, stream>>>(W1, W1t);
  k_cvt_w2  <<<(128 * 384) / 256, 256, 0, stream>>>(W2, W2t);

  k_hist    <<<(NE + 255) / 256, 256, 0, stream>>>(dst, et, cur);
  k_scanA   <<<782, 256, 0, stream>>>(cur, psum);
  k_scanB   <<<1, 1024, 0, stream>>>(psum);
  k_scanC   <<<782, 256, 0, stream>>>(cur, psum, csroff);
  k_scatter <<<(NE + 255) / 256, 256, 0, stream>>>(src, dst, et, cur, bucket);

  k_edge_msg<<<NN / 32, 256, 0, stream>>>(xb, Wt, csroff, bucket, rel_bias, msg);
  k_mlp1    <<<NN / 32, 256, 0, stream>>>(xb, msg, W1t, b1, midb);
  k_mlp2    <<<NN / 32, 256, 0, stream>>>(xb, midb, W2t, b2, out);
}

// Round 5
// 635.883 us; speedup vs baseline: 1.5344x; 1.5344x over previous
//
#include <hip/hip_runtime.h>

#define NN 100000   // nodes
#define NE 640000   // edges
#define RR 8        // relations
#define NBIN 800000 // NN*8 csr bins
// D = HID = OUT = 128 hard-coded below.

typedef unsigned short u16;
typedef u16 u16x4 __attribute__((ext_vector_type(4)));
typedef u16 u16x8 __attribute__((ext_vector_type(8)));
typedef __bf16 bf16x8 __attribute__((ext_vector_type(8)));
typedef float f32x4 __attribute__((ext_vector_type(4)));

// ---- workspace layout (bytes) ----
#define OFF_MSG     0u          // fp32 N*128            = 51,200,000
#define OFF_MIDB    51200000u   // bf16 N*256            = 51,200,000
#define OFF_XB      102400000u  // bf16 N*128            = 25,600,000
#define OFF_WT      128000000u  // bf16 [9][128o][128d]  = 294,912 (8 rels + loop_w)
#define OFF_W1T     128296960u  // bf16 [256o][256i]     = 131,072
#define OFF_W2T     128428032u  // bf16 [128o][384i]     = 98,304
#define OFF_BUCKET  128527360u  // uint E (packed src|rel<<17) = 2,560,000
#define OFF_CSROFF  131088384u  // int  NBIN+1           = 3,200,004
#define OFF_CUR     134289408u  // int  NBIN             = 3,200,000
#define OFF_PSUM    137490432u  // int  1024

__device__ inline u16 f2bf(float f) {
  unsigned u = __float_as_uint(f);
  u += 0x7FFF + ((u >> 16) & 1);   // round-to-nearest-even
  return (u16)(u >> 16);
}
__device__ inline float bf2f(u16 h) { return __uint_as_float(((unsigned)h) << 16); }

// bin = dst*8 + rel  -> a node's 8 bins are contiguous; a 32-node tile's
// edges are one contiguous range in bucket[]
__device__ inline int edge_bin(int d, int r) { return d * 8 + r; }

// ---------------- dtype prep ----------------
__global__ void k_cvt_x(const float* __restrict__ x, u16* __restrict__ xb) {
  const int i = (blockIdx.x * 256 + threadIdx.x) * 4;
  const float4 v = *(const float4*)(x + i);
  u16x4 o;
  o.x = f2bf(v.x); o.y = f2bf(v.y); o.z = f2bf(v.z); o.w = f2bf(v.w);
  *(u16x4*)(xb + i) = o;
}

// Wt[r][o][d]: r<8 from W_rel, r==8 from loop_w
__global__ void k_cvt_wrel(const float* __restrict__ W, const float* __restrict__ Lw,
                           u16* __restrict__ Wt) {
  const int idx = blockIdx.x * 256 + threadIdx.x;      // 9*16384 total
  const int r = idx >> 14, o = (idx >> 7) & 127, d = idx & 127;
  Wt[idx] = f2bf(r < 8 ? W[(r << 14) + (d << 7) + o] : Lw[(d << 7) + o]);
}

__global__ void k_cvt_w1(const float* __restrict__ W1, u16* __restrict__ W1t) {
  const int idx = blockIdx.x * 256 + threadIdx.x;      // 65536
  const int o = idx >> 8, i = idx & 255;
  W1t[idx] = f2bf(W1[i * 256 + o]);
}

__global__ void k_cvt_w2(const float* __restrict__ W2, u16* __restrict__ W2t) {
  const int idx = blockIdx.x * 256 + threadIdx.x;      // 49152
  const int o = idx / 384, i = idx % 384;
  W2t[idx] = f2bf(W2[i * 128 + o]);
}

// ---------------- CSR build ----------------
__global__ void k_hist(const int* __restrict__ dst, const int* __restrict__ et,
                       int* __restrict__ cnt) {
  const int e = blockIdx.x * 256 + threadIdx.x;
  if (e < NE) atomicAdd(&cnt[edge_bin(dst[e], et[e])], 1);
}

__global__ void k_scanA(const int* __restrict__ cnt, int* __restrict__ psum) {
  __shared__ int sc[256];
  const int tid = threadIdx.x, base = blockIdx.x * 1024 + tid * 4;
  int s = 0;
#pragma unroll
  for (int t = 0; t < 4; ++t) { const int i = base + t; if (i < NBIN) s += cnt[i]; }
  sc[tid] = s; __syncthreads();
  for (int d = 128; d > 0; d >>= 1) {
    if (tid < d) sc[tid] += sc[tid + d];
    __syncthreads();
  }
  if (tid == 0) psum[blockIdx.x] = sc[0];
}

__global__ void k_scanB(int* __restrict__ psum) {
  __shared__ int sc[1024];
  const int tid = threadIdx.x;
  const int v = (tid < 782) ? psum[tid] : 0;
  sc[tid] = v; __syncthreads();
  for (int d = 1; d < 1024; d <<= 1) {
    const int t = (tid >= d) ? sc[tid - d] : 0;
    __syncthreads();
    sc[tid] += t;
    __syncthreads();
  }
  if (tid < 782) psum[tid] = sc[tid] - v;   // exclusive
}

__global__ void k_scanC(int* __restrict__ cnt /*=cur*/, const int* __restrict__ psum,
                        int* __restrict__ off) {
  __shared__ int sc[256];
  const int tid = threadIdx.x, base = blockIdx.x * 1024 + tid * 4;
  int c[4], s = 0;
#pragma unroll
  for (int t = 0; t < 4; ++t) {
    const int i = base + t;
    c[t] = (i < NBIN) ? cnt[i] : 0;
    s += c[t];
  }
  sc[tid] = s; __syncthreads();
  for (int d = 1; d < 256; d <<= 1) {
    const int t = (tid >= d) ? sc[tid - d] : 0;
    __syncthreads();
    sc[tid] += t;
    __syncthreads();
  }
  int run = psum[blockIdx.x] + sc[tid] - s;   // exclusive thread base
#pragma unroll
  for (int t = 0; t < 4; ++t) {
    const int i = base + t;
    if (i < NBIN) { off[i] = run; cnt[i] = run; run += c[t]; }
  }
  if (blockIdx.x == 0 && tid == 0) off[NBIN] = NE;
}

__global__ void k_scatter(const int* __restrict__ src, const int* __restrict__ dst,
                          const int* __restrict__ et, int* __restrict__ cur,
                          unsigned* __restrict__ bucket) {
  const int e = blockIdx.x * 256 + threadIdx.x;
  if (e < NE) {
    const int d = dst[e], r = et[e];
    const int pos = atomicAdd(&cur[edge_bin(d, r)], 1);
    bucket[pos] = (unsigned)src[e] | ((unsigned)r << 17);   // src 17b | rel 3b
  }
}

// ---------------- fused edge-aggregate + transform + self-loop + bias ----
// One block per 32 dst nodes; thread = (node, 16-col group) with EXCLUSIVE
// ownership of its LDS A-tile slots (no atomics). 2 phases x 4 relations.
// Gather: flat walk over the node's 4-rel contiguous range, 4-deep
// software-pipelined global loads; rel boundary -> flush fp32 acc to bf16
// LDS tile. Zero global atomics, 5 barriers.
#define ATS 136    // A-tile row stride (u16): 68 words, %32=4 -> 2-way (free)
#define WCAP 448   // staged bucket words per tile (mean 205, +17 sigma)
__global__ __launch_bounds__(256, 4) void k_edge_msg(
    const u16* __restrict__ xb, const u16* __restrict__ Wt,
    const int* __restrict__ csroff, const unsigned* __restrict__ bucket,
    const float* __restrict__ rel_bias, float* __restrict__ msg) {
  __shared__ u16 At[4 * 32 * ATS];     // 34,816 B
  __shared__ unsigned wlds[WCAP];      // 1,792 B
  const int tid = threadIdx.x;
  const int v0 = blockIdx.x * 32;
  const int wave = tid >> 6, lane = tid & 63;
  const int l16 = lane & 15, quad = lane >> 4;
  const int rt = wave & 1, cb = (wave >> 1) << 6;
  const int si = tid >> 3, sj = tid & 7;

  const int gbase = csroff[v0 * 8];
  const int ntot  = csroff[v0 * 8 + 256] - gbase;

  f32x4 acc[4] = {};

  // ---- self-loop: A-frags straight from global xb ----
  {
    const u16* xp = xb + ((size_t)(v0 + rt * 16 + l16) << 7) + quad * 8;
    bf16x8 afr[4];
#pragma unroll
    for (int t = 0; t < 4; ++t) afr[t] = *(const bf16x8*)(xp + t * 32);
    const u16* wb = Wt + (8 << 14);
#pragma unroll
    for (int c = 0; c < 4; ++c) {
      const u16* wp = wb + (size_t)(cb + c * 16 + l16) * 128 + quad * 8;
#pragma unroll
      for (int t = 0; t < 4; ++t)
        acc[c] = __builtin_amdgcn_mfma_f32_16x16x32_bf16(afr[t], *(const bf16x8*)(wp + t * 32), acc[c], 0, 0, 0);
    }
  }

  // ---- stage packed edge words (coalesced) ----
  {
    const int nst = ntot < WCAP ? ntot : WCAP;
    for (int i = tid; i < nst; i += 256) wlds[i] = bucket[gbase + i];
  }
  __syncthreads();

#pragma unroll
  for (int ph = 0; ph < 2; ++ph) {
    // pre-zero OWN slots in the 4 tiles (exclusive; no sync needed)
    {
      const u16x8 z = {0, 0, 0, 0, 0, 0, 0, 0};
#pragma unroll
      for (int q = 0; q < 4; ++q) {
        u16* dp = &At[q * (32 * ATS) + si * ATS + sj * 16];
        *(u16x8*)dp = z;
        *(u16x8*)(dp + 8) = z;
      }
    }

    // flat pipelined walk of this node's 4-rel range
    {
      const int pbeg = csroff[v0 * 8 + si * 8 + ph * 4] - gbase;
      const int pend = csroff[v0 * 8 + si * 8 + ph * 4 + 4] - gbase;
      const int n = pend - pbeg;
      float a[16] = {};
      int crel = -1;
      unsigned wv[4];
      u16x8 h0[4], h1[4];
      // prime 4 slots (constant slot index -> stays in VGPRs)
#pragma unroll
      for (int j = 0; j < 4; ++j) {
        if (j < n) {
          const int p = pbeg + j;
          const unsigned w = (p < WCAP) ? wlds[p] : bucket[gbase + p];
          wv[j] = w;
          const u16* xp = xb + ((size_t)(w & 0x1FFFFu) << 7) + sj * 16;
          h0[j] = *(const u16x8*)xp;
          h1[j] = *(const u16x8*)(xp + 8);
        }
      }
      for (int ib = 0; ib < n; ib += 4) {
#pragma unroll
        for (int j = 0; j < 4; ++j) {
          const int i = ib + j;
          if (i < n) {
            const int r = (int)((wv[j] >> 17) & 7u);
            if (r != crel) {
              if (crel >= 0) {     // flush accumulated bin -> bf16 LDS tile
                u16x8 o0, o1;
#pragma unroll
                for (int t = 0; t < 8; ++t) { o0[t] = f2bf(a[t]); o1[t] = f2bf(a[8 + t]); }
                u16* dp = &At[(crel & 3) * (32 * ATS) + si * ATS + sj * 16];
                *(u16x8*)dp = o0;
                *(u16x8*)(dp + 8) = o1;
              }
#pragma unroll
              for (int t = 0; t < 16; ++t) a[t] = 0.f;
              crel = r;
            }
#pragma unroll
            for (int t = 0; t < 8; ++t) { a[t] += bf2f(h0[j][t]); a[8 + t] += bf2f(h1[j][t]); }
            // refill slot j with edge i+4
            const int p = i + 4;
            if (p < n) {
              const int pp = pbeg + p;
              const unsigned w = (pp < WCAP) ? wlds[pp] : bucket[gbase + pp];
              wv[j] = w;
              const u16* xp = xb + ((size_t)(w & 0x1FFFFu) << 7) + sj * 16;
              h0[j] = *(const u16x8*)xp;
              h1[j] = *(const u16x8*)(xp + 8);
            }
          }
        }
      }
      if (crel >= 0) {
        u16x8 o0, o1;
#pragma unroll
        for (int t = 0; t < 8; ++t) { o0[t] = f2bf(a[t]); o1[t] = f2bf(a[8 + t]); }
        u16* dp = &At[(crel & 3) * (32 * ATS) + si * ATS + sj * 16];
        *(u16x8*)dp = o0;
        *(u16x8*)(dp + 8) = o1;
      }
    }
    __syncthreads();

    // MFMA over the 4 relation tiles
#pragma unroll
    for (int q = 0; q < 4; ++q) {
      bf16x8 afr[4];
#pragma unroll
      for (int t = 0; t < 4; ++t)
        afr[t] = *(const bf16x8*)&At[q * (32 * ATS) + (rt * 16 + l16) * ATS + quad * 8 + t * 32];
      const u16* wb = Wt + ((ph * 4 + q) << 14);
#pragma unroll
      for (int c = 0; c < 4; ++c) {
        const u16* wp = wb + (size_t)(cb + c * 16 + l16) * 128 + quad * 8;
#pragma unroll
        for (int t = 0; t < 4; ++t)
          acc[c] = __builtin_amdgcn_mfma_f32_16x16x32_bf16(afr[t], *(const bf16x8*)(wp + t * 32), acc[c], 0, 0, 0);
      }
    }
    __syncthreads();
  }

  // ---- epilogue: + rel_bias, single fp32 write ----
#pragma unroll
  for (int c = 0; c < 4; ++c) {
    const int col = cb + c * 16 + l16;
    const float bias = rel_bias[col];
#pragma unroll
    for (int reg = 0; reg < 4; ++reg) {
      const int row = v0 + rt * 16 + quad * 4 + reg;
      msg[(size_t)row * 128 + col] = acc[c][reg] + bias;
    }
  }
}

// ---------------- mid = tanh([x | msg] @ W1 + b1), bf16 MFMA -------------
#define A1S 264   // 256+8 u16: 132 words, %32=4
__global__ __launch_bounds__(256) void k_mlp1(
    const u16* __restrict__ xb, const float* __restrict__ msg,
    const u16* __restrict__ W1t, const float* __restrict__ b1,
    u16* __restrict__ midb) {
  __shared__ u16 At[32 * A1S];
  const int tid = threadIdx.x;
  const int v0 = blockIdx.x * 32;
  const int si = tid >> 3, sj = tid & 7;

  { // stage x -> cols 0..127
    const u16* xp = xb + ((size_t)(v0 + si) << 7) + sj * 16;
    *(u16x8*)&At[si * A1S + sj * 16]     = *(const u16x8*)(xp);
    *(u16x8*)&At[si * A1S + sj * 16 + 8] = *(const u16x8*)(xp + 8);
  }
  { // stage msg (fp32) -> cols 128..255
    const float* mp = msg + (size_t)(v0 + si) * 128 + sj * 16;
    u16x8 o0, o1;
#pragma unroll
    for (int t = 0; t < 8; ++t) { o0[t] = f2bf(mp[t]); o1[t] = f2bf(mp[8 + t]); }
    *(u16x8*)&At[si * A1S + 128 + sj * 16]     = o0;
    *(u16x8*)&At[si * A1S + 128 + sj * 16 + 8] = o1;
  }
  __syncthreads();

  const int wave = tid >> 6, lane = tid & 63;
  const int l16 = lane & 15, quad = lane >> 4;
  const int rt = wave & 1, ch = (wave >> 1) << 7;

  f32x4 acc[8] = {};
  for (int kt = 0; kt < 8; ++kt) {
    const bf16x8 af = *(const bf16x8*)&At[(rt * 16 + l16) * A1S + kt * 32 + quad * 8];
#pragma unroll
    for (int ct = 0; ct < 8; ++ct) {
      const u16* wp = W1t + (size_t)(ch + ct * 16 + l16) * 256 + kt * 32 + quad * 8;
      acc[ct] = __builtin_amdgcn_mfma_f32_16x16x32_bf16(af, *(const bf16x8*)(wp), acc[ct], 0, 0, 0);
    }
  }

#pragma unroll
  for (int ct = 0; ct < 8; ++ct) {
    const int col = ch + ct * 16 + l16;
    const float bias = b1[col];
#pragma unroll
    for (int reg = 0; reg < 4; ++reg) {
      const int row = v0 + rt * 16 + quad * 4 + reg;
      midb[(size_t)row * 256 + col] = f2bf(tanhf(acc[ct][reg] + bias));
    }
  }
}

// ---------------- out = [x | mid] @ W2 + b2, bf16 MFMA -------------------
#define A2S 392   // 384+8 u16: 196 words, %32=4
__global__ __launch_bounds__(256) void k_mlp2(
    const u16* __restrict__ xb, const u16* __restrict__ midb,
    const u16* __restrict__ W2t, const float* __restrict__ b2,
    float* __restrict__ out) {
  __shared__ u16 At[32 * A2S];
  const int tid = threadIdx.x;
  const int v0 = blockIdx.x * 32;
  const int si = tid >> 3, sj = tid & 7;

  { // stage x -> cols 0..127
    const u16* xp = xb + ((size_t)(v0 + si) << 7) + sj * 16;
    *(u16x8*)&At[si * A2S + sj * 16]     = *(const u16x8*)(xp);
    *(u16x8*)&At[si * A2S + sj * 16 + 8] = *(const u16x8*)(xp + 8);
  }
  { // stage mid -> cols 128..383 (32 u16 per thread)
    const u16* mp = midb + ((size_t)(v0 + si) << 8) + sj * 32;
#pragma unroll
    for (int t = 0; t < 4; ++t)
      *(u16x8*)&At[si * A2S + 128 + sj * 32 + t * 8] = *(const u16x8*)(mp + t * 8);
  }
  __syncthreads();

  const int wave = tid >> 6, lane = tid & 63;
  const int l16 = lane & 15, quad = lane >> 4;
  const int rt = wave & 1, cb = (wave >> 1) << 6;

  f32x4 acc[4] = {};
  for (int kt = 0; kt < 12; ++kt) {
    const bf16x8 af = *(const bf16x8*)&At[(rt * 16 + l16) * A2S + kt * 32 + quad * 8];
#pragma unroll
    for (int ct = 0; ct < 4; ++ct) {
      const u16* wp = W2t + (size_t)(cb + ct * 16 + l16) * 384 + kt * 32 + quad * 8;
      acc[ct] = __builtin_amdgcn_mfma_f32_16x16x32_bf16(af, *(const bf16x8*)(wp), acc[ct], 0, 0, 0);
    }
  }

#pragma unroll
  for (int ct = 0; ct < 4; ++ct) {
    const int col = cb + ct * 16 + l16;
    const float bias = b2[col];
#pragma unroll
    for (int reg = 0; reg < 4; ++reg) {
      const int row = v0 + rt * 16 + quad * 4 + reg;
      out[(size_t)row * 128 + col] = acc[ct][reg] + bias;
    }
  }
}

extern "C" void kernel_launch(void* const* d_in, const int* in_sizes, int n_in,
                              void* d_out, int out_size, void* d_ws, size_t ws_size,
                              hipStream_t stream) {
  (void)in_sizes; (void)n_in; (void)out_size; (void)ws_size;
  const float* x        = (const float*)d_in[0];
  const int*   src      = (const int*)d_in[1];
  const int*   dst      = (const int*)d_in[2];
  const int*   et       = (const int*)d_in[3];
  const float* W_rel    = (const float*)d_in[4];
  const float* loop_w   = (const float*)d_in[5];
  const float* rel_bias = (const float*)d_in[6];
  const float* W1       = (const float*)d_in[7];
  const float* b1       = (const float*)d_in[8];
  const float* W2       = (const float*)d_in[9];
  const float* b2       = (const float*)d_in[10];
  float* out = (float*)d_out;

  char* ws = (char*)d_ws;
  float*    msg    = (float*)(ws + OFF_MSG);
  u16*      midb   = (u16*)(ws + OFF_MIDB);
  u16*      xb     = (u16*)(ws + OFF_XB);
  u16*      Wt     = (u16*)(ws + OFF_WT);
  u16*      W1t    = (u16*)(ws + OFF_W1T);
  u16*      W2t    = (u16*)(ws + OFF_W2T);
  unsigned* bucket = (unsigned*)(ws + OFF_BUCKET);
  int*      csroff = (int*)(ws + OFF_CSROFF);
  int*      cur    = (int*)(ws + OFF_CUR);
  int*      psum   = (int*)(ws + OFF_PSUM);

  hipMemsetAsync(cur, 0, (size_t)NBIN * 4, stream);

  k_cvt_x   <<<(NN * 128) / 1024, 256, 0, stream>>>(x, xb);
  k_cvt_wrel<<<(9 * 16384) / 256, 256, 0, stream>>>(W_rel, loop_w, Wt);
  k_cvt_w1  <<<(256 * 256) / 256, 256, 0, stream>>>(W1, W1t);
  k_cvt_w2  <<<(128 * 384) / 256, 256, 0, stream>>>(W2, W2t);

  k_hist    <<<(NE + 255) / 256, 256, 0, stream>>>(dst, et, cur);
  k_scanA   <<<782, 256, 0, stream>>>(cur, psum);
  k_scanB   <<<1, 1024, 0, stream>>>(psum);
  k_scanC   <<<782, 256, 0, stream>>>(cur, psum, csroff);
  k_scatter <<<(NE + 255) / 256, 256, 0, stream>>>(src, dst, et, cur, bucket);

  k_edge_msg<<<NN / 32, 256, 0, stream>>>(xb, Wt, csroff, bucket, rel_bias, msg);
  k_mlp1    <<<NN / 32, 256, 0, stream>>>(xb, msg, W1t, b1, midb);
  k_mlp2    <<<NN / 32, 256, 0, stream>>>(xb, midb, W2t, b2, out);
}